// Round 5
// baseline (45.562 us; speedup 1.0000x reference)
//
#include <hip/hip_runtime.h>

#define NUM_BINS 10
#define GRID1 2048
#define BLOCK 256
// 16,777,216 elems / (2048*256 threads) = 32 elems/thread = 8 float4 quad-pairs.
// R4: loads forced to stay batched via asm volatile global_load_dwordx4 ->
// 16 KB in flight per wave (compiler provably un-batched them in R2/R3:
// VGPR_Count stayed 24/36). Explicit vmcnt(0) + sched_barrier fences per
// guide rule #18 (compiler does not track vmcnt for asm loads).
// Packed 8-bit counter fields: max 32/thread -> 128 after 2 butterfly
// rounds; 16-bit fields after full wave reduce hold <= 2048. No overflow.

typedef float f32x4 __attribute__((ext_vector_type(4)));

__device__ __forceinline__ void accum_quad(f32x4 r, f32x4 g, int p[5]) {
    #pragma unroll
    for (int j = 0; j < 4; ++j) {
        float rv = r[j];
        float gv = g[j];
        int b = (int)(rv * 10.0f);             // inputs in [0,1)
        b = b > NUM_BINS - 1 ? NUM_BINS - 1 : b;
        int c = (gv > 0.5f) ? b : b + NUM_BINS;  // ano: 0..9, nor: 10..19
        int inc = 1 << ((c & 3) << 3);
        int sel = c >> 2;                       // 0..4
        #pragma unroll
        for (int k = 0; k < 5; ++k)
            p[k] += (sel == k) ? inc : 0;       // cmp + cndmask + add
    }
}

__global__ __launch_bounds__(BLOCK) void hist_asm(
    const float* __restrict__ res,
    const float* __restrict__ gt,
    int* __restrict__ out,   // [20], pre-zeroed
    int n4)
{
    const int tid  = threadIdx.x;
    const int lane = tid & 63;
    const int wv   = tid >> 6;

    int p[5] = {0, 0, 0, 0, 0};

    const f32x4* __restrict__ res4 = (const f32x4*)res;
    const f32x4* __restrict__ gt4  = (const f32x4*)gt;

    const int S    = GRID1 * BLOCK;            // quad stride
    const int base = blockIdx.x * BLOCK + tid;

    if (n4 == S * 8) {
        const f32x4* rp = res4 + base;
        const f32x4* gp = gt4 + base;
        f32x4 r[8], g[8];
        // Issue ALL 16 loads back-to-back. asm volatile statements cannot be
        // reordered among themselves, deleted, or sunk by any pass.
        #pragma unroll
        for (int k = 0; k < 8; ++k) {
            asm volatile("global_load_dwordx4 %0, %1, off"
                         : "=&v"(r[k]) : "v"(rp + (size_t)k * S));
            asm volatile("global_load_dwordx4 %0, %1, off"
                         : "=&v"(g[k]) : "v"(gp + (size_t)k * S));
        }
        // Rule #18: compiler doesn't model vmcnt for asm loads and WILL hoist
        // consumers past a bare waitcnt; fence both sides with sched_barrier.
        __builtin_amdgcn_sched_barrier(0);
        asm volatile("s_waitcnt vmcnt(0)" ::: "memory");
        __builtin_amdgcn_sched_barrier(0);
        #pragma unroll
        for (int k = 0; k < 8; ++k)
            accum_quad(r[k], g[k], p);
    } else {
        // Generic grid-stride fallback (compiler-managed loads/waitcnts).
        for (int i = base; i < n4; i += S)
            accum_quad(res4[i], gt4[i], p);
    }

    // Wave butterfly reduce: 2 rounds on packed 8-bit (fields <= 128)...
    #pragma unroll
    for (int k = 0; k < 5; ++k) {
        p[k] += __shfl_xor(p[k], 1, 64);
        p[k] += __shfl_xor(p[k], 2, 64);
    }
    // ...widen to 16-bit fields (10 regs x 2 halves)...
    int q[10];
    #pragma unroll
    for (int k = 0; k < 5; ++k) {
        q[2 * k]     = p[k] & 0x00FF00FF;          // counters 4k+0 (lo16), 4k+2 (hi16)
        q[2 * k + 1] = (p[k] >> 8) & 0x00FF00FF;   // counters 4k+1 (lo16), 4k+3 (hi16)
    }
    // ...4 more rounds on 16-bit packed (fields <= 2048).
    #pragma unroll
    for (int m = 4; m <= 32; m <<= 1) {
        #pragma unroll
        for (int k = 0; k < 10; ++k)
            q[k] += __shfl_xor(q[k], m, 64);
    }

    __shared__ int part[4][2 * NUM_BINS];
    if (lane == 0) {
        #pragma unroll
        for (int k = 0; k < 5; ++k) {
            part[wv][4 * k + 0] = q[2 * k] & 0xFFFF;
            part[wv][4 * k + 2] = (int)((unsigned)q[2 * k] >> 16);
            part[wv][4 * k + 1] = q[2 * k + 1] & 0xFFFF;
            part[wv][4 * k + 3] = (int)((unsigned)q[2 * k + 1] >> 16);
        }
    }
    __syncthreads();
    // One wave-instruction of global atomics per block (20 lanes, 2 cache lines).
    if (tid < 2 * NUM_BINS) {
        int s = part[0][tid] + part[1][tid] + part[2][tid] + part[3][tid];
        if (s) atomicAdd(&out[tid], s);
    }
}

extern "C" void kernel_launch(void* const* d_in, const int* in_sizes, int n_in,
                              void* d_out, int out_size, void* d_ws, size_t ws_size,
                              hipStream_t stream) {
    const float* res = (const float*)d_in[0];
    const float* gt  = (const float*)d_in[1];
    int* out = (int*)d_out;

    const int n  = in_sizes[0];   // 16,777,216 (divisible by 4)
    const int n4 = n >> 2;

    // Harness poisons d_out with 0xAA; zero it on-stream (capture-safe).
    hipMemsetAsync(d_out, 0, 2 * NUM_BINS * sizeof(int), stream);
    hist_asm<<<GRID1, BLOCK, 0, stream>>>(res, gt, out, n4);
}